// Round 18
// baseline (27.611 us; speedup 1.0000x reference)
//
#include <hip/hip_runtime.h>

#define BS 4
#define DM 1024
#define LL 2048
#define NS 64
#define TT 64        // chunk length
#define NCH 16       // chunks per block (half of 32)
#define PAD 68       // LDS row stride for 64-wide mats (136B -> conflict-light)
#define UPAD 1036    // U row stride (shorts) for 1024 t: dword stride 518 = 6 mod 32
#define DT 16        // d-rows per block

typedef __attribute__((ext_vector_type(8))) short bf8;     // 8 bf16 (4 VGPR)
typedef __attribute__((ext_vector_type(4))) float f32x4;   // mfma C/D

__device__ __forceinline__ unsigned short f2bf(float x) {  // fp32 -> bf16 RNE
    unsigned u = __float_as_uint(x);
    return (unsigned short)((u + 0x7FFFu + ((u >> 16) & 1u)) >> 16);
}

__device__ __forceinline__ bf8 ld_frag(const short* p) {   // 8 contiguous bf16 (8B aligned)
    short4 a = *(const short4*)p;
    short4 b = *(const short4*)(p + 4);
    bf8 f;
    f[0]=a.x; f[1]=a.y; f[2]=a.z; f[3]=a.w;
    f[4]=b.x; f[5]=b.y; f[6]=b.z; f[7]=b.w;
    return f;
}

// LDS-only barrier (proven correct r15/r16): orders Hl/Ul DS traffic without
// draining global stores (T4: never vmcnt(0) in the loop).
__device__ __forceinline__ void bar_lds() {
    asm volatile("s_waitcnt lgkmcnt(0)" ::: "memory");
    __builtin_amdgcn_s_barrier();
    __builtin_amdgcn_sched_barrier(0);                  // rule-18 guard
}

// 512 blocks = (b, 16-d tile, L-half p) x 768 thr -> 2 blocks/CU, 24 waves/CU.
// p=0: chunks 0..15. p=1: chunks 16..31, with redundant scan warm-up over 0..15
// (stage first half, scan it barrier-free, re-stage own half). Zero MFMA waste.
// Waves 0-3: scan (Hloc = P@U, h_run in regs), one iteration AHEAD.
// Waves 4-11: Y = L@U + V@h_init, 2 chunks per barrier, 8 iterations.
__global__ __launch_bounds__(768) void ssm_one(const float* __restrict__ u,
                                               const float* __restrict__ A,
                                               const float* __restrict__ Bv,
                                               const float* __restrict__ Cv,
                                               float* __restrict__ y) {
    __shared__ short Ul[DT * UPAD];       // 33152 B: u half-row-block, bf16
    __shared__ short Pl[64 * PAD];        // 8704 B
    __shared__ short LV[2 * 64 * PAD];    // 17408 B: fp32 scratch, then L | V bf16
    __shared__ short Hl[2][2][DT * PAD];  // 8704 B: ring of h_init (buf x chunk-sub)
    __shared__ float kf[64];
    __shared__ float part[256];

    const int tid = threadIdx.x;
    const int bx  = blockIdx.x;           // 512 = b(4) * dt(64) * p(2)
    const int p   = bx & 1;
    const int dt  = (bx >> 1) & 63;
    const int b   = bx >> 7;
    const int wid = tid >> 6;
    const int l   = tid & 63;
    const int lm  = l & 15, lq = l >> 4, lk8 = lq * 8;

    const float* ubase = u + ((size_t)(b * DM + dt * DT)) * LL;

    // ---- stage phase A: chunks 0..15 (t in [0,1024)) -> Ul (both p) ----
#pragma unroll
    for (int k = 0; k < 6; ++k) {
        const int idx = tid + k * 768;            // 4096 float4 slots
        if (idx < 4096) {
            const int r  = idx >> 8;              // 256 float4 per row
            const int t4 = (idx & 255) * 4;
            const float4 v = *(const float4*)(ubase + (size_t)r * LL + t4);
            short4 h = make_short4((short)f2bf(v.x), (short)f2bf(v.y),
                                   (short)f2bf(v.z), (short)f2bf(v.w));
            *(short4*)&Ul[r * UPAD + t4] = h;
        }
    }

    // ---- builders: wid<4 -> P;  wid 4-7 -> kernel-tap scratch (verbatim, verified) ----
    if (wid < 4) {
        // P[i][sigma] = Bv_i * a_i^(63-sigma)
        const int i = tid & 63, sq_ = tid >> 6, q = 3 - sq_, s0 = sq_ * 16;
        const float a  = A[i * (NS + 1)];
        const float bv = Bv[i];
        const float a2 = a*a, a4 = a2*a2, a8 = a4*a4, a16 = a8*a8, a32 = a16*a16;
        float pw = bv * ((q & 1) ? a16 : 1.f) * ((q & 2) ? a32 : 1.f);
#pragma unroll
        for (int jj = 15; jj >= 0; --jj) { Pl[i * PAD + s0 + jj] = (short)f2bf(pw); pw *= a; }
    } else if (wid < 8) {
        // scratch[delta][i] = w_i * a_i^delta
        const int t2 = tid - 256;
        float* scr = (float*)LV;
        const int im = t2 & 63, dq = t2 >> 6, D0 = dq * 16;
        const float a  = A[im * (NS + 1)];
        const float wv = Bv[im] * Cv[im];
        const float a2 = a*a, a4 = a2*a2, a8 = a4*a4, a16 = a8*a8, a32 = a16*a16;
        float pw = wv * ((dq & 1) ? a16 : 1.f) * ((dq & 2) ? a32 : 1.f);
#pragma unroll
        for (int dd = 0; dd < 16; ++dd) { scr[(D0 + dd) * PAD + im] = pw; pw *= a; }
    }
    __syncthreads();
    if (wid >= 4 && wid < 8) {   // k[delta] = sum_i scratch[delta][i]
        const int t2 = tid - 256;
        float* scr = (float*)LV;
        const int Dl = t2 & 63, q = t2 >> 6;
        float ssum = 0.f;
#pragma unroll
        for (int ii = 0; ii < 16; ++ii) ssum += scr[Dl * PAD + q * 16 + ii];
        part[t2] = ssum;
    }
    __syncthreads();
    if (tid >= 256 && tid < 320) {
        const int t2 = tid - 256;
        kf[t2] = part[t2] + part[t2 + 64] + part[t2 + 128] + part[t2 + 192];
    }
    __syncthreads();
    if (wid >= 4 && wid < 8) {
        const int t2 = tid - 256;
        short* Ll = LV;                               // L: lower-tri Toeplitz of kf
        const int r = t2 >> 2, sb = (t2 & 3) * 16;
#pragma unroll
        for (int s2 = 0; s2 < 16; ++s2) {
            const int sc = sb + s2;
            Ll[r * PAD + sc] = (r >= sc) ? (short)f2bf(kf[r - sc]) : (short)0;
        }
        short* Vl = LV + 64 * PAD;                    // V[r][i] = C_i a_i^(r+1)
        const int im = t2 & 63, rq = t2 >> 6, r0 = rq * 16;
        const float a  = A[im * (NS + 1)];
        const float cv = Cv[im];
        const float a2 = a*a, a4 = a2*a2, a8 = a4*a4, a16 = a8*a8, a32 = a16*a16;
        float pw = cv * a * ((rq & 1) ? a16 : 1.f) * ((rq & 2) ? a32 : 1.f);
#pragma unroll
        for (int rr = 0; rr < 16; ++rr) { Vl[(r0 + rr) * PAD + im] = (short)f2bf(pw); pw *= a; }
    }
    __syncthreads();

    // ---- per-wave invariant fragments + scan state ----
    bf8 fA0, fA1, fB0, fB1;
    float aT[4];
    f32x4 hrun = (f32x4){0.f, 0.f, 0.f, 0.f};
    if (wid < 4) {
        fA0 = ld_frag(&Pl[(wid * 16 + lm) * PAD + lk8]);
        fA1 = ld_frag(&Pl[(wid * 16 + lm) * PAD + 32 + lk8]);
        fB0 = fA0; fB1 = fA1;   // unused
#pragma unroll
        for (int r = 0; r < 4; ++r) {       // aT = a_i^64 for my 4 acc rows
            const int i = wid * 16 + lq * 4 + r;
            float x = A[i * (NS + 1)];
#pragma unroll
            for (int q = 0; q < 6; ++q) x = x * x;
            aT[r] = x;
        }
    } else {
        const int wt = (wid - 4) & 3;
        fA0 = ld_frag(&LV[(wt * 16 + lm) * PAD + lk8]);              // L
        fA1 = ld_frag(&LV[(wt * 16 + lm) * PAD + 32 + lk8]);
        fB0 = ld_frag(&LV[64 * PAD + (wt * 16 + lm) * PAD + lk8]);   // V
        fB1 = ld_frag(&LV[64 * PAD + (wt * 16 + lm) * PAD + 32 + lk8]);
        aT[0] = aT[1] = aT[2] = aT[3] = 0.f;
    }

    // ---- p=1: redundant scan warm-up over chunks 0..15, then re-stage own half ----
    if (p == 1) {
        if (wid < 4) {
            for (int lc = 0; lc < NCH; ++lc) {
                const int tb = lc * TT;
                const bf8 bU0 = ld_frag(&Ul[lm * UPAD + tb + lk8]);
                const bf8 bU1 = ld_frag(&Ul[lm * UPAD + tb + 32 + lk8]);
                f32x4 hl = (f32x4){0.f, 0.f, 0.f, 0.f};
                hl = __builtin_amdgcn_mfma_f32_16x16x32_bf16(fA0, bU0, hl, 0, 0, 0);
                hl = __builtin_amdgcn_mfma_f32_16x16x32_bf16(fA1, bU1, hl, 0, 0, 0);
#pragma unroll
                for (int r = 0; r < 4; ++r) hrun[r] = fmaf(aT[r], hrun[r], hl[r]);
            }
        }
        __syncthreads();    // warm-up reads complete before overwrite
        // stage phase B: chunks 16..31 (t in [1024,2048)) into the same buffer
#pragma unroll
        for (int k = 0; k < 6; ++k) {
            const int idx = tid + k * 768;
            if (idx < 4096) {
                const int r  = idx >> 8;
                const int t4 = (idx & 255) * 4;
                const float4 v = *(const float4*)(ubase + (size_t)r * LL + 1024 + t4);
                short4 h = make_short4((short)f2bf(v.x), (short)f2bf(v.y),
                                       (short)f2bf(v.z), (short)f2bf(v.w));
                *(short4*)&Ul[r * UPAD + t4] = h;
            }
        }
        __syncthreads();
    }

    // ---- scan prologue: local chunks 0,1 -> Hl[0][0..1] ----
    if (wid < 4) {
        const int i0 = wid * 16 + lq * 4;
#pragma unroll
        for (int s = 0; s < 2; ++s) {
            short4 hh = make_short4((short)f2bf(hrun[0]), (short)f2bf(hrun[1]),
                                    (short)f2bf(hrun[2]), (short)f2bf(hrun[3]));
            *(short4*)&Hl[0][s][lm * PAD + i0] = hh;
            const int tb = s * TT;
            const bf8 bU0 = ld_frag(&Ul[lm * UPAD + tb + lk8]);
            const bf8 bU1 = ld_frag(&Ul[lm * UPAD + tb + 32 + lk8]);
            f32x4 hl = (f32x4){0.f, 0.f, 0.f, 0.f};
            hl = __builtin_amdgcn_mfma_f32_16x16x32_bf16(fA0, bU0, hl, 0, 0, 0);
            hl = __builtin_amdgcn_mfma_f32_16x16x32_bf16(fA1, bU1, hl, 0, 0, 0);
#pragma unroll
            for (int r = 0; r < 4; ++r) hrun[r] = fmaf(aT[r], hrun[r], hl[r]);
        }
    }
    __syncthreads();

    // ---- main loop: 8 iterations, 2 local chunks each, 1 LDS-only barrier each ----
    const int tgbase = p * (NCH * TT);    // global t offset of this block's half
    for (int k = 0; k < 8; ++k) {
        if (wid < 4) {
            // scan one iteration ahead: local chunks 2k+2, 2k+3 -> Hl[(k+1)&1]
            const int c2 = 2 * k + 2;
            if (c2 < NCH) {
                const int i0 = wid * 16 + lq * 4;
#pragma unroll
                for (int s = 0; s < 2; ++s) {
                    short4 hh = make_short4((short)f2bf(hrun[0]), (short)f2bf(hrun[1]),
                                            (short)f2bf(hrun[2]), (short)f2bf(hrun[3]));
                    *(short4*)&Hl[(k + 1) & 1][s][lm * PAD + i0] = hh;
                    const int tb = (c2 + s) * TT;
                    const bf8 bU0 = ld_frag(&Ul[lm * UPAD + tb + lk8]);
                    const bf8 bU1 = ld_frag(&Ul[lm * UPAD + tb + 32 + lk8]);
                    f32x4 hl = (f32x4){0.f, 0.f, 0.f, 0.f};
                    hl = __builtin_amdgcn_mfma_f32_16x16x32_bf16(fA0, bU0, hl, 0, 0, 0);
                    hl = __builtin_amdgcn_mfma_f32_16x16x32_bf16(fA1, bU1, hl, 0, 0, 0);
#pragma unroll
                    for (int r = 0; r < 4; ++r) hrun[r] = fmaf(aT[r], hrun[r], hl[r]);
                }
            }
        } else {
            // Y waves: local chunk lc = 2k + sub, h_init from Hl[k&1][sub]
            const int sub = (wid - 4) >> 2;
            const int wt  = (wid - 4) & 3;
            const int lc  = 2 * k + sub;
            const int tb  = lc * TT;
            const bf8 bU0 = ld_frag(&Ul[lm * UPAD + tb + lk8]);
            const bf8 bU1 = ld_frag(&Ul[lm * UPAD + tb + 32 + lk8]);
            const bf8 bH0 = ld_frag(&Hl[k & 1][sub][lm * PAD + lk8]);
            const bf8 bH1 = ld_frag(&Hl[k & 1][sub][lm * PAD + 32 + lk8]);
            f32x4 yac = (f32x4){0.f, 0.f, 0.f, 0.f};
            yac = __builtin_amdgcn_mfma_f32_16x16x32_bf16(fA0, bU0, yac, 0, 0, 0);
            yac = __builtin_amdgcn_mfma_f32_16x16x32_bf16(fA1, bU1, yac, 0, 0, 0);
            yac = __builtin_amdgcn_mfma_f32_16x16x32_bf16(fB0, bH0, yac, 0, 0, 0);
            yac = __builtin_amdgcn_mfma_f32_16x16x32_bf16(fB1, bH1, yac, 0, 0, 0);
            const int t0 = tgbase + tb + wt * 16 + lq * 4;   // C rows = t (contiguous 4)
            *(f32x4*)&y[((size_t)(b * DM + dt * DT + lm)) * LL + t0] = yac;
        }
        bar_lds();
    }
}

extern "C" void kernel_launch(void* const* d_in, const int* in_sizes, int n_in,
                              void* d_out, int out_size, void* d_ws, size_t ws_size,
                              hipStream_t stream) {
    const float* u  = (const float*)d_in[0];
    const float* A  = (const float*)d_in[1];
    const float* Bv = (const float*)d_in[2];
    const float* Cv = (const float*)d_in[3];
    float* y = (float*)d_out;

    ssm_one<<<BS * (DM / DT) * 2, 768, 0, stream>>>(u, A, Bv, Cv, y);
}

// Round 19
// 21.863 us; speedup vs baseline: 1.2629x; 1.2629x over previous
//
#include <hip/hip_runtime.h>

#define BS 4
#define DM 1024
#define LL 2048
#define NS 64
#define CC 32        // chunks
#define TT 64        // chunk length
#define PAD 68       // LDS row stride for 64-wide mats (136B -> conflict-light)
#define UPAD 2060    // U row stride (shorts): dword stride 1030 -> spread banks
#define DT 16        // d-rows per block

typedef __attribute__((ext_vector_type(8))) short bf8;     // 8 bf16 (4 VGPR)
typedef __attribute__((ext_vector_type(4))) float f32x4;   // mfma C/D

__device__ __forceinline__ unsigned short f2bf(float x) {  // fp32 -> bf16 RNE
    unsigned u = __float_as_uint(x);
    return (unsigned short)((u + 0x7FFFu + ((u >> 16) & 1u)) >> 16);
}

__device__ __forceinline__ bf8 ld_frag(const short* p) {   // 8 contiguous bf16 (8B aligned)
    short4 a = *(const short4*)p;
    short4 b = *(const short4*)(p + 4);
    bf8 f;
    f[0]=a.x; f[1]=a.y; f[2]=a.z; f[3]=a.w;
    f[4]=b.x; f[5]=b.y; f[6]=b.z; f[7]=b.w;
    return f;
}

// LDS-only barrier (correctness proven r15-r18): orders the Hl handoff without
// draining in-flight global stores (T4: never vmcnt(0) inside the loop).
__device__ __forceinline__ void bar_lds() {
    asm volatile("s_waitcnt lgkmcnt(0)" ::: "memory");
    __builtin_amdgcn_s_barrier();
    __builtin_amdgcn_sched_barrier(0);                  // rule-18 guard
}

// r14 structure (best: 21.8us) + bar_lds in the main loop (isolated delta).
// 256 blocks (b x 16-d tile) x 768 thr (12 waves, 3/SIMD).
// Waves 0-3: scan (Hloc = P@U, h_run in regs), one iteration AHEAD.
// Waves 4-11: Y = L@U + V@h_init, 2 chunks per barrier.
__global__ __launch_bounds__(768) void ssm_one(const float* __restrict__ u,
                                               const float* __restrict__ A,
                                               const float* __restrict__ Bv,
                                               const float* __restrict__ Cv,
                                               float* __restrict__ y) {
    __shared__ short Ul[DT * UPAD];       // 65920 B: u row-block, bf16
    __shared__ short Pl[64 * PAD];        // 8704 B
    __shared__ short LV[2 * 64 * PAD];    // 17408 B: fp32 scratch, then L | V bf16
    __shared__ short Hl[2][2][DT * PAD];  // 8704 B: ring of h_init (buf x chunk-sub)
    __shared__ float kf[64];
    __shared__ float part[256];

    const int tid = threadIdx.x;
    const int bx  = blockIdx.x;           // 256 = b(4) * dt(64)
    const int dt  = bx & 63, b = bx >> 6;
    const int wid = tid >> 6;
    const int l   = tid & 63;
    const int lm  = l & 15, lq = l >> 4, lk8 = lq * 8;

    // ---- stage U: 16 rows x 2048 t, fp32 -> bf16 (full, upfront; r14-verbatim) ----
    {
        const float* ubase = u + ((size_t)(b * DM + dt * DT)) * LL;
#pragma unroll
        for (int k = 0; k < 11; ++k) {
            const int idx = tid + k * 768;          // 8192 float4 slots
            if (idx < 8192) {
                const int r  = idx >> 9;
                const int t4 = (idx & 511) * 4;
                const float4 v = *(const float4*)(ubase + (size_t)r * LL + t4);
                short4 h = make_short4((short)f2bf(v.x), (short)f2bf(v.y),
                                       (short)f2bf(v.z), (short)f2bf(v.w));
                *(short4*)&Ul[r * UPAD + t4] = h;
            }
        }
    }

    // ---- builders: wid<4 -> P;  wid 4-7 -> kernel-tap scratch (verbatim, verified) ----
    if (wid < 4) {
        // P[i][sigma] = Bv_i * a_i^(63-sigma)
        const int i = tid & 63, sq_ = tid >> 6, q = 3 - sq_, s0 = sq_ * 16;
        const float a  = A[i * (NS + 1)];
        const float bv = Bv[i];
        const float a2 = a*a, a4 = a2*a2, a8 = a4*a4, a16 = a8*a8, a32 = a16*a16;
        float p = bv * ((q & 1) ? a16 : 1.f) * ((q & 2) ? a32 : 1.f);
#pragma unroll
        for (int jj = 15; jj >= 0; --jj) { Pl[i * PAD + s0 + jj] = (short)f2bf(p); p *= a; }
    } else if (wid < 8) {
        // scratch[delta][i] = w_i * a_i^delta
        const int t2 = tid - 256;
        float* scr = (float*)LV;
        const int im = t2 & 63, dq = t2 >> 6, D0 = dq * 16;
        const float a  = A[im * (NS + 1)];
        const float wv = Bv[im] * Cv[im];
        const float a2 = a*a, a4 = a2*a2, a8 = a4*a4, a16 = a8*a8, a32 = a16*a16;
        float p = wv * ((dq & 1) ? a16 : 1.f) * ((dq & 2) ? a32 : 1.f);
#pragma unroll
        for (int dd = 0; dd < 16; ++dd) { scr[(D0 + dd) * PAD + im] = p; p *= a; }
    }
    __syncthreads();
    if (wid >= 4 && wid < 8) {   // k[delta] = sum_i scratch[delta][i]
        const int t2 = tid - 256;
        float* scr = (float*)LV;
        const int Dl = t2 & 63, q = t2 >> 6;
        float ssum = 0.f;
#pragma unroll
        for (int ii = 0; ii < 16; ++ii) ssum += scr[Dl * PAD + q * 16 + ii];
        part[t2] = ssum;
    }
    __syncthreads();
    if (tid >= 256 && tid < 320) {
        const int t2 = tid - 256;
        kf[t2] = part[t2] + part[t2 + 64] + part[t2 + 128] + part[t2 + 192];
    }
    __syncthreads();
    if (wid >= 4 && wid < 8) {
        const int t2 = tid - 256;
        short* Ll = LV;                               // L: lower-tri Toeplitz of kf
        const int r = t2 >> 2, sb = (t2 & 3) * 16;
#pragma unroll
        for (int s2 = 0; s2 < 16; ++s2) {
            const int sc = sb + s2;
            Ll[r * PAD + sc] = (r >= sc) ? (short)f2bf(kf[r - sc]) : (short)0;
        }
        short* Vl = LV + 64 * PAD;                    // V[r][i] = C_i a_i^(r+1)
        const int im = t2 & 63, rq = t2 >> 6, r0 = rq * 16;
        const float a  = A[im * (NS + 1)];
        const float cv = Cv[im];
        const float a2 = a*a, a4 = a2*a2, a8 = a4*a4, a16 = a8*a8, a32 = a16*a16;
        float p = cv * a * ((rq & 1) ? a16 : 1.f) * ((rq & 2) ? a32 : 1.f);
#pragma unroll
        for (int rr = 0; rr < 16; ++rr) { Vl[(r0 + rr) * PAD + im] = (short)f2bf(p); p *= a; }
    }
    __syncthreads();

    // ---- per-wave invariant fragments + scan state ----
    bf8 fA0, fA1, fB0, fB1;
    float aT[4];
    f32x4 hrun = (f32x4){0.f, 0.f, 0.f, 0.f};
    if (wid < 4) {
        fA0 = ld_frag(&Pl[(wid * 16 + lm) * PAD + lk8]);
        fA1 = ld_frag(&Pl[(wid * 16 + lm) * PAD + 32 + lk8]);
        fB0 = fA0; fB1 = fA1;   // unused
#pragma unroll
        for (int r = 0; r < 4; ++r) {       // aT = a_i^64 for my 4 acc rows
            const int i = wid * 16 + lq * 4 + r;
            float x = A[i * (NS + 1)];
#pragma unroll
            for (int q = 0; q < 6; ++q) x = x * x;
            aT[r] = x;
        }
    } else {
        const int wt = (wid - 4) & 3;
        fA0 = ld_frag(&LV[(wt * 16 + lm) * PAD + lk8]);              // L
        fA1 = ld_frag(&LV[(wt * 16 + lm) * PAD + 32 + lk8]);
        fB0 = ld_frag(&LV[64 * PAD + (wt * 16 + lm) * PAD + lk8]);   // V
        fB1 = ld_frag(&LV[64 * PAD + (wt * 16 + lm) * PAD + 32 + lk8]);
        aT[0] = aT[1] = aT[2] = aT[3] = 0.f;
    }

    // ---- scan prologue: chunks 0,1 -> Hl[0][0..1] ----
    if (wid < 4) {
        const int i0 = wid * 16 + lq * 4;
#pragma unroll
        for (int s = 0; s < 2; ++s) {
            short4 hh = make_short4((short)f2bf(hrun[0]), (short)f2bf(hrun[1]),
                                    (short)f2bf(hrun[2]), (short)f2bf(hrun[3]));
            *(short4*)&Hl[0][s][lm * PAD + i0] = hh;
            const int tb = s * TT;
            const bf8 bU0 = ld_frag(&Ul[lm * UPAD + tb + lk8]);
            const bf8 bU1 = ld_frag(&Ul[lm * UPAD + tb + 32 + lk8]);
            f32x4 hl = (f32x4){0.f, 0.f, 0.f, 0.f};
            hl = __builtin_amdgcn_mfma_f32_16x16x32_bf16(fA0, bU0, hl, 0, 0, 0);
            hl = __builtin_amdgcn_mfma_f32_16x16x32_bf16(fA1, bU1, hl, 0, 0, 0);
#pragma unroll
            for (int r = 0; r < 4; ++r) hrun[r] = fmaf(aT[r], hrun[r], hl[r]);
        }
    }
    __syncthreads();

    // ---- main loop: 16 iterations, 2 chunks each, 1 LDS-only barrier each ----
    for (int k = 0; k < 16; ++k) {
        if (wid < 4) {
            // scan one iteration ahead: chunks 2k+2, 2k+3 -> Hl[(k+1)&1]
            const int c2 = 2 * k + 2;
            if (c2 < CC) {
                const int i0 = wid * 16 + lq * 4;
#pragma unroll
                for (int s = 0; s < 2; ++s) {
                    short4 hh = make_short4((short)f2bf(hrun[0]), (short)f2bf(hrun[1]),
                                            (short)f2bf(hrun[2]), (short)f2bf(hrun[3]));
                    *(short4*)&Hl[(k + 1) & 1][s][lm * PAD + i0] = hh;
                    const int tb = (c2 + s) * TT;
                    const bf8 bU0 = ld_frag(&Ul[lm * UPAD + tb + lk8]);
                    const bf8 bU1 = ld_frag(&Ul[lm * UPAD + tb + 32 + lk8]);
                    f32x4 hl = (f32x4){0.f, 0.f, 0.f, 0.f};
                    hl = __builtin_amdgcn_mfma_f32_16x16x32_bf16(fA0, bU0, hl, 0, 0, 0);
                    hl = __builtin_amdgcn_mfma_f32_16x16x32_bf16(fA1, bU1, hl, 0, 0, 0);
#pragma unroll
                    for (int r = 0; r < 4; ++r) hrun[r] = fmaf(aT[r], hrun[r], hl[r]);
                }
            }
        } else {
            // Y waves: chunk c = 2k + sub, h_init from Hl[k&1][sub]
            const int sub = (wid - 4) >> 2;
            const int wt  = (wid - 4) & 3;
            const int c   = 2 * k + sub;
            const int tb  = c * TT;
            const bf8 bU0 = ld_frag(&Ul[lm * UPAD + tb + lk8]);
            const bf8 bU1 = ld_frag(&Ul[lm * UPAD + tb + 32 + lk8]);
            const bf8 bH0 = ld_frag(&Hl[k & 1][sub][lm * PAD + lk8]);
            const bf8 bH1 = ld_frag(&Hl[k & 1][sub][lm * PAD + 32 + lk8]);
            f32x4 yac = (f32x4){0.f, 0.f, 0.f, 0.f};
            yac = __builtin_amdgcn_mfma_f32_16x16x32_bf16(fA0, bU0, yac, 0, 0, 0);
            yac = __builtin_amdgcn_mfma_f32_16x16x32_bf16(fA1, bU1, yac, 0, 0, 0);
            yac = __builtin_amdgcn_mfma_f32_16x16x32_bf16(fB0, bH0, yac, 0, 0, 0);
            yac = __builtin_amdgcn_mfma_f32_16x16x32_bf16(fB1, bH1, yac, 0, 0, 0);
            const int t0 = tb + wt * 16 + lq * 4;     // C rows = t (contiguous 4)
            *(f32x4*)&y[((size_t)(b * DM + dt * DT + lm)) * LL + t0] = yac;
        }
        bar_lds();
    }
}

extern "C" void kernel_launch(void* const* d_in, const int* in_sizes, int n_in,
                              void* d_out, int out_size, void* d_ws, size_t ws_size,
                              hipStream_t stream) {
    const float* u  = (const float*)d_in[0];
    const float* A  = (const float*)d_in[1];
    const float* Bv = (const float*)d_in[2];
    const float* Cv = (const float*)d_in[3];
    float* y = (float*)d_out;

    ssm_one<<<BS * (DM / DT), 768, 0, stream>>>(u, A, Bv, Cv, y);
}

// Round 20
// 21.535 us; speedup vs baseline: 1.2822x; 1.0153x over previous
//
#include <hip/hip_runtime.h>

#define BS 4
#define DM 1024
#define LL 2048
#define NS 64
#define CC 32        // chunks
#define TT 64        // chunk length
#define PAD 68       // LDS row stride for 64-wide mats (136B -> conflict-light)
#define UPAD 2060    // U row stride (shorts): dword stride 1030 -> spread banks
#define DT 16        // d-rows per block

typedef __attribute__((ext_vector_type(8))) short bf8;     // 8 bf16 (4 VGPR)
typedef __attribute__((ext_vector_type(4))) float f32x4;   // mfma C/D

__device__ __forceinline__ unsigned short f2bf(float x) {  // fp32 -> bf16 RNE
    unsigned u = __float_as_uint(x);
    return (unsigned short)((u + 0x7FFFu + ((u >> 16) & 1u)) >> 16);
}

__device__ __forceinline__ bf8 ld_frag(const short* p) {   // 8 contiguous bf16 (8B aligned)
    short4 a = *(const short4*)p;
    short4 b = *(const short4*)(p + 4);
    bf8 f;
    f[0]=a.x; f[1]=a.y; f[2]=a.z; f[3]=a.w;
    f[4]=b.x; f[5]=b.y; f[6]=b.z; f[7]=b.w;
    return f;
}

// LDS-only barrier (correctness proven r15-r19): orders LDS traffic without
// draining in-flight global loads/stores (T4).
__device__ __forceinline__ void bar_lds() {
    asm volatile("s_waitcnt lgkmcnt(0)" ::: "memory");
    __builtin_amdgcn_s_barrier();
    __builtin_amdgcn_sched_barrier(0);                  // rule-18 guard
}

// r19 structure with builders OVERLAPPED under staging:
//   waves 0-7 (512 thr): stage U in 4 t-major batches (chunks 8j..8j+7 each)
//   waves 8-11 (256 thr): P -> scratch -> kf-reduce -> L,V builder chain
// sharing the same 4 bar_lds as phase boundaries. Loop body verbatim r19.
__global__ __launch_bounds__(768) void ssm_one(const float* __restrict__ u,
                                               const float* __restrict__ A,
                                               const float* __restrict__ Bv,
                                               const float* __restrict__ Cv,
                                               float* __restrict__ y) {
    __shared__ short Ul[DT * UPAD];       // 65920 B: u row-block, bf16
    __shared__ short Pl[64 * PAD];        // 8704 B
    __shared__ short LV[2 * 64 * PAD];    // 17408 B: fp32 scratch, then L | V bf16
    __shared__ short Hl[2][2][DT * PAD];  // 8704 B: ring of h_init (buf x chunk-sub)
    __shared__ float kf[64];
    __shared__ float part[256];

    const int tid = threadIdx.x;
    const int bx  = blockIdx.x;           // 256 = b(4) * dt(64)
    const int dt  = bx & 63, b = bx >> 6;
    const int wid = tid >> 6;
    const int l   = tid & 63;
    const int lm  = l & 15, lq = l >> 4, lk8 = lq * 8;

    const float* ubase = u + ((size_t)(b * DM + dt * DT)) * LL;
    const bool stager = (tid < 512);
    const int  t2     = tid - 512;        // builder thread id (waves 8-11)

    // staging helper: batch j stages t-range [512j, 512j+512) of all 16 rows
    auto stage_batch = [&](int j) {
#pragma unroll
        for (int i = 0; i < 4; ++i) {
            const int s  = tid + i * 512;           // 0..2047
            const int r  = s >> 7;                  // row 0..15
            const int tq = (s & 127) * 4 + j * 512; // 32 lanes -> 512B contiguous
            const float4 v = *(const float4*)(ubase + (size_t)r * LL + tq);
            short4 h = make_short4((short)f2bf(v.x), (short)f2bf(v.y),
                                   (short)f2bf(v.z), (short)f2bf(v.w));
            *(short4*)&Ul[r * UPAD + tq] = h;
        }
    };

    // ---- phase 1: stagers batch 0  ||  builders: P fill then scratch fill ----
    if (stager) {
        stage_batch(0);
    } else {
        // P[i][sigma] = Bv_i * a_i^(63-sigma)   (verbatim, verified)
        {
            const int i = t2 & 63, sq_ = t2 >> 6, q = 3 - sq_, s0 = sq_ * 16;
            const float a  = A[i * (NS + 1)];
            const float bv = Bv[i];
            const float a2 = a*a, a4 = a2*a2, a8 = a4*a4, a16 = a8*a8, a32 = a16*a16;
            float p = bv * ((q & 1) ? a16 : 1.f) * ((q & 2) ? a32 : 1.f);
#pragma unroll
            for (int jj = 15; jj >= 0; --jj) { Pl[i * PAD + s0 + jj] = (short)f2bf(p); p *= a; }
        }
        // scratch[delta][i] = w_i * a_i^delta   (verbatim, verified)
        {
            float* scr = (float*)LV;
            const int im = t2 & 63, dq = t2 >> 6, D0 = dq * 16;
            const float a  = A[im * (NS + 1)];
            const float wv = Bv[im] * Cv[im];
            const float a2 = a*a, a4 = a2*a2, a8 = a4*a4, a16 = a8*a8, a32 = a16*a16;
            float p = wv * ((dq & 1) ? a16 : 1.f) * ((dq & 2) ? a32 : 1.f);
#pragma unroll
            for (int dd = 0; dd < 16; ++dd) { scr[(D0 + dd) * PAD + im] = p; p *= a; }
        }
    }
    bar_lds();

    // ---- phase 2: stagers batch 1  ||  builders: part reduce ----
    if (stager) {
        stage_batch(1);
    } else {
        float* scr = (float*)LV;
        const int Dl = t2 & 63, q = t2 >> 6;
        float ssum = 0.f;
#pragma unroll
        for (int ii = 0; ii < 16; ++ii) ssum += scr[Dl * PAD + q * 16 + ii];
        part[t2] = ssum;
    }
    bar_lds();

    // ---- phase 3: stagers batch 2  ||  builders: kf ----
    if (stager) {
        stage_batch(2);
    } else if (t2 < 64) {
        kf[t2] = part[t2] + part[t2 + 64] + part[t2 + 128] + part[t2 + 192];
    }
    bar_lds();

    // ---- phase 4: stagers batch 3  ||  builders: L, V fill ----
    if (stager) {
        stage_batch(3);
    } else {
        short* Ll = LV;                               // L: lower-tri Toeplitz of kf
        const int r = t2 >> 2, sb = (t2 & 3) * 16;
#pragma unroll
        for (int s2 = 0; s2 < 16; ++s2) {
            const int sc = sb + s2;
            Ll[r * PAD + sc] = (r >= sc) ? (short)f2bf(kf[r - sc]) : (short)0;
        }
        short* Vl = LV + 64 * PAD;                    // V[r][i] = C_i a_i^(r+1)
        const int im = t2 & 63, rq = t2 >> 6, r0 = rq * 16;
        const float a  = A[im * (NS + 1)];
        const float cv = Cv[im];
        const float a2 = a*a, a4 = a2*a2, a8 = a4*a4, a16 = a8*a8, a32 = a16*a16;
        float p = cv * a * ((rq & 1) ? a16 : 1.f) * ((rq & 2) ? a32 : 1.f);
#pragma unroll
        for (int rr = 0; rr < 16; ++rr) { Vl[(r0 + rr) * PAD + im] = (short)f2bf(p); p *= a; }
    }
    bar_lds();

    // ---- per-wave invariant fragments + scan state (verbatim r19) ----
    bf8 fA0, fA1, fB0, fB1;
    float aT[4];
    f32x4 hrun = (f32x4){0.f, 0.f, 0.f, 0.f};
    if (wid < 4) {
        fA0 = ld_frag(&Pl[(wid * 16 + lm) * PAD + lk8]);
        fA1 = ld_frag(&Pl[(wid * 16 + lm) * PAD + 32 + lk8]);
        fB0 = fA0; fB1 = fA1;   // unused
#pragma unroll
        for (int r = 0; r < 4; ++r) {       // aT = a_i^64 for my 4 acc rows
            const int i = wid * 16 + lq * 4 + r;
            float x = A[i * (NS + 1)];
#pragma unroll
            for (int q = 0; q < 6; ++q) x = x * x;
            aT[r] = x;
        }
    } else {
        const int wt = (wid - 4) & 3;
        fA0 = ld_frag(&LV[(wt * 16 + lm) * PAD + lk8]);              // L
        fA1 = ld_frag(&LV[(wt * 16 + lm) * PAD + 32 + lk8]);
        fB0 = ld_frag(&LV[64 * PAD + (wt * 16 + lm) * PAD + lk8]);   // V
        fB1 = ld_frag(&LV[64 * PAD + (wt * 16 + lm) * PAD + 32 + lk8]);
        aT[0] = aT[1] = aT[2] = aT[3] = 0.f;
    }

    // ---- scan prologue: chunks 0,1 -> Hl[0][0..1] ----
    if (wid < 4) {
        const int i0 = wid * 16 + lq * 4;
#pragma unroll
        for (int s = 0; s < 2; ++s) {
            short4 hh = make_short4((short)f2bf(hrun[0]), (short)f2bf(hrun[1]),
                                    (short)f2bf(hrun[2]), (short)f2bf(hrun[3]));
            *(short4*)&Hl[0][s][lm * PAD + i0] = hh;
            const int tb = s * TT;
            const bf8 bU0 = ld_frag(&Ul[lm * UPAD + tb + lk8]);
            const bf8 bU1 = ld_frag(&Ul[lm * UPAD + tb + 32 + lk8]);
            f32x4 hl = (f32x4){0.f, 0.f, 0.f, 0.f};
            hl = __builtin_amdgcn_mfma_f32_16x16x32_bf16(fA0, bU0, hl, 0, 0, 0);
            hl = __builtin_amdgcn_mfma_f32_16x16x32_bf16(fA1, bU1, hl, 0, 0, 0);
#pragma unroll
            for (int r = 0; r < 4; ++r) hrun[r] = fmaf(aT[r], hrun[r], hl[r]);
        }
    }
    bar_lds();

    // ---- main loop: 16 iterations, 2 chunks each, 1 LDS-only barrier each ----
    for (int k = 0; k < 16; ++k) {
        if (wid < 4) {
            // scan one iteration ahead: chunks 2k+2, 2k+3 -> Hl[(k+1)&1]
            const int c2 = 2 * k + 2;
            if (c2 < CC) {
                const int i0 = wid * 16 + lq * 4;
#pragma unroll
                for (int s = 0; s < 2; ++s) {
                    short4 hh = make_short4((short)f2bf(hrun[0]), (short)f2bf(hrun[1]),
                                            (short)f2bf(hrun[2]), (short)f2bf(hrun[3]));
                    *(short4*)&Hl[(k + 1) & 1][s][lm * PAD + i0] = hh;
                    const int tb = (c2 + s) * TT;
                    const bf8 bU0 = ld_frag(&Ul[lm * UPAD + tb + lk8]);
                    const bf8 bU1 = ld_frag(&Ul[lm * UPAD + tb + 32 + lk8]);
                    f32x4 hl = (f32x4){0.f, 0.f, 0.f, 0.f};
                    hl = __builtin_amdgcn_mfma_f32_16x16x32_bf16(fA0, bU0, hl, 0, 0, 0);
                    hl = __builtin_amdgcn_mfma_f32_16x16x32_bf16(fA1, bU1, hl, 0, 0, 0);
#pragma unroll
                    for (int r = 0; r < 4; ++r) hrun[r] = fmaf(aT[r], hrun[r], hl[r]);
                }
            }
        } else {
            // Y waves: chunk c = 2k + sub, h_init from Hl[k&1][sub]
            const int sub = (wid - 4) >> 2;
            const int wt  = (wid - 4) & 3;
            const int c   = 2 * k + sub;
            const int tb  = c * TT;
            const bf8 bU0 = ld_frag(&Ul[lm * UPAD + tb + lk8]);
            const bf8 bU1 = ld_frag(&Ul[lm * UPAD + tb + 32 + lk8]);
            const bf8 bH0 = ld_frag(&Hl[k & 1][sub][lm * PAD + lk8]);
            const bf8 bH1 = ld_frag(&Hl[k & 1][sub][lm * PAD + 32 + lk8]);
            f32x4 yac = (f32x4){0.f, 0.f, 0.f, 0.f};
            yac = __builtin_amdgcn_mfma_f32_16x16x32_bf16(fA0, bU0, yac, 0, 0, 0);
            yac = __builtin_amdgcn_mfma_f32_16x16x32_bf16(fA1, bU1, yac, 0, 0, 0);
            yac = __builtin_amdgcn_mfma_f32_16x16x32_bf16(fB0, bH0, yac, 0, 0, 0);
            yac = __builtin_amdgcn_mfma_f32_16x16x32_bf16(fB1, bH1, yac, 0, 0, 0);
            const int t0 = tb + wt * 16 + lq * 4;     // C rows = t (contiguous 4)
            *(f32x4*)&y[((size_t)(b * DM + dt * DT + lm)) * LL + t0] = yac;
        }
        bar_lds();
    }
}

extern "C" void kernel_launch(void* const* d_in, const int* in_sizes, int n_in,
                              void* d_out, int out_size, void* d_ws, size_t ws_size,
                              hipStream_t stream) {
    const float* u  = (const float*)d_in[0];
    const float* A  = (const float*)d_in[1];
    const float* Bv = (const float*)d_in[2];
    const float* Cv = (const float*)d_in[3];
    float* y = (float*)d_out;

    ssm_one<<<BS * (DM / DT), 768, 0, stream>>>(u, A, Bv, Cv, y);
}